// Round 1
// baseline (511.780 us; speedup 1.0000x reference)
//
#include <hip/hip_runtime.h>

// Problem constants (from reference setup_inputs)
#define BB 8      // batch
#define RR 16     // rotations
#define NN 6144   // gpc systems (vertices)
#define FF 128    // features

// One wave (64 lanes) per (b, n) pair.
// Each lane owns 2 consecutive features (float2): 64 * 2 = 128 = FF.
// For each rotation r: coalesced float2 load (512 B / wave), partial sum of
// squares, 6-level shuffle reduction -> full squared norm, keep running-best
// vector fragment in registers. Strict '>' keeps the FIRST max (matches
// jnp.argmax tie-break). Final coalesced float2 store of the winner.
__global__ __launch_bounds__(256) void amp_kernel(const float* __restrict__ in,
                                                  float* __restrict__ out) {
    const int tid  = blockIdx.x * 256 + threadIdx.x;
    const int wave = tid >> 6;          // global wave id = (b, n) pair
    const int lane = tid & 63;

    const int b = wave / NN;
    const int n = wave - b * NN;

    // &in[b][0][n][lane*2]
    const size_t base    = (((size_t)b * RR) * NN + n) * (size_t)FF + (lane << 1);
    const size_t rstride = (size_t)NN * FF;   // stride between rotations

    float2 best_v  = make_float2(0.f, 0.f);
    float  best_sum = -1.f;                   // norms are >= 0, so r=0 always wins first

    #pragma unroll
    for (int r = 0; r < RR; ++r) {
        const float2 v = *(const float2*)(in + base + (size_t)r * rstride);
        float s = v.x * v.x + v.y * v.y;
        // full-wave (64-lane) butterfly sum
        s += __shfl_xor(s, 1);
        s += __shfl_xor(s, 2);
        s += __shfl_xor(s, 4);
        s += __shfl_xor(s, 8);
        s += __shfl_xor(s, 16);
        s += __shfl_xor(s, 32);
        if (s > best_sum) {                   // strict: first max wins, like argmax
            best_sum = s;
            best_v   = v;
        }
    }

    // &out[b][n][lane*2]
    float* o = out + ((size_t)b * NN + n) * (size_t)FF + (lane << 1);
    *(float2*)o = best_v;
}

extern "C" void kernel_launch(void* const* d_in, const int* in_sizes, int n_in,
                              void* d_out, int out_size, void* d_ws, size_t ws_size,
                              hipStream_t stream) {
    const float* in  = (const float*)d_in[0];
    float*       out = (float*)d_out;

    // B*N waves, 4 waves (256 threads) per block
    const int n_waves  = BB * NN;             // 49152
    const int n_blocks = n_waves / 4;         // 12288

    amp_kernel<<<dim3(n_blocks), dim3(256), 0, stream>>>(in, out);
}

// Round 3
// 496.542 us; speedup vs baseline: 1.0307x; 1.0307x over previous
//
#include <hip/hip_runtime.h>

// Problem constants (from reference setup_inputs)
#define BB 8      // batch
#define RR 16     // rotations
#define NN 6144   // gpc systems (vertices)
#define FF 128    // features

// Native clang vector type — required for __builtin_nontemporal_load/store
// (HIP_vector_type float4 is a struct and is rejected by the builtin).
typedef float f32x4 __attribute__((ext_vector_type(4)));

// Half-wave (32 lanes) per (b, n) row; one wave handles 2 consecutive rows.
// Each lane owns 4 consecutive features (float4): 32 * 4 = 128 = FF.
// Per rotation: one coalesced global_load_dwordx4 (1 KB / wave), partial sum
// of squares, 5-level shuffle reduction within each 32-lane half (xor 1..16
// never crosses the half boundary), keep running-best f32x4 in registers.
// Strict '>' keeps the FIRST max (matches jnp.argmax tie-break).
__global__ __launch_bounds__(256) void amp_kernel(const float* __restrict__ in,
                                                  float* __restrict__ out) {
    const int tid     = blockIdx.x * 256 + threadIdx.x;
    const int wave    = tid >> 6;        // global wave id = pair of rows
    const int lane    = tid & 63;
    const int half    = lane >> 5;       // 0: row n, 1: row n+1
    const int sublane = lane & 31;       // feature group within row

    const int b      = wave / (NN / 2);
    const int n_pair = wave - b * (NN / 2);
    const int n      = n_pair * 2 + half;

    // &in[b][0][n][sublane*4]
    const size_t base    = (((size_t)b * RR) * NN + n) * (size_t)FF + (sublane << 2);
    const size_t rstride = (size_t)NN * FF;   // stride between rotations

    f32x4 best_v   = (f32x4)(0.f);
    float best_sum = -1.f;                    // norms >= 0, so r=0 always wins first

    #pragma unroll
    for (int r = 0; r < RR; ++r) {
        const f32x4 v = __builtin_nontemporal_load(
            (const f32x4*)(in + base + (size_t)r * rstride));
        float s = v.x * v.x + v.y * v.y + v.z * v.z + v.w * v.w;
        // 32-lane butterfly sum (stays within each half of the wave)
        s += __shfl_xor(s, 1);
        s += __shfl_xor(s, 2);
        s += __shfl_xor(s, 4);
        s += __shfl_xor(s, 8);
        s += __shfl_xor(s, 16);
        if (s > best_sum) {                   // strict: first max wins, like argmax
            best_sum = s;
            best_v   = v;
        }
    }

    // &out[b][n][sublane*4]
    f32x4* o = (f32x4*)(out + ((size_t)b * NN + n) * (size_t)FF + (sublane << 2));
    __builtin_nontemporal_store(best_v, o);
}

extern "C" void kernel_launch(void* const* d_in, const int* in_sizes, int n_in,
                              void* d_out, int out_size, void* d_ws, size_t ws_size,
                              hipStream_t stream) {
    const float* in  = (const float*)d_in[0];
    float*       out = (float*)d_out;

    // B*N/2 waves (each wave does 2 rows), 4 waves (256 threads) per block
    const int n_waves  = BB * NN / 2;         // 24576
    const int n_blocks = n_waves / 4;         // 6144

    amp_kernel<<<dim3(n_blocks), dim3(256), 0, stream>>>(in, out);
}

// Round 4
// 495.541 us; speedup vs baseline: 1.0328x; 1.0020x over previous
//
#include <hip/hip_runtime.h>

// Problem constants (from reference setup_inputs)
#define BB 8      // batch
#define RR 16     // rotations
#define NN 6144   // gpc systems (vertices)
#define FF 128    // features

// Native clang vector type — required for __builtin_nontemporal_load/store.
typedef float f32x4 __attribute__((ext_vector_type(4)));

// Quarter-wave (16 lanes) per (b, n) row; one wave handles 4 consecutive rows.
// Each lane owns 8 features, split as two coalesced dwordx4 groups:
//   group A: features [sublane*4 .. sublane*4+4)        (row bytes   0..255)
//   group B: features [64 + sublane*4 .. 64+sublane*4+4) (row bytes 256..511)
// Per rotation: 2 coalesced 16B/lane loads (2 KB / wave), per-lane sum of 8
// squares, 4-level butterfly (xor 1,2,4,8 — stays inside each 16-lane
// quarter), keep running-best 8 floats in registers.
// Strict '>' keeps the FIRST max (matches jnp.argmax tie-break).
__global__ __launch_bounds__(256) void amp_kernel(const float* __restrict__ in,
                                                  float* __restrict__ out) {
    const int tid     = blockIdx.x * 256 + threadIdx.x;
    const int wave    = tid >> 6;        // global wave id = group of 4 rows
    const int lane    = tid & 63;
    const int quarter = lane >> 4;       // 0..3: which row within the wave
    const int sublane = lane & 15;       // feature group within row

    const int b     = wave / (NN / 4);
    const int n_grp = wave - b * (NN / 4);
    const int n     = n_grp * 4 + quarter;

    // &in[b][0][n][sublane*4]
    const size_t base    = (((size_t)b * RR) * NN + n) * (size_t)FF + (sublane << 2);
    const size_t rstride = (size_t)NN * FF;   // stride between rotations

    f32x4 best_a   = (f32x4)(0.f);
    f32x4 best_b   = (f32x4)(0.f);
    float best_sum = -1.f;                    // norms >= 0, so r=0 always wins first

    #pragma unroll
    for (int r = 0; r < RR; ++r) {
        const float* p = in + base + (size_t)r * rstride;
        const f32x4 va = __builtin_nontemporal_load((const f32x4*)p);
        const f32x4 vb = __builtin_nontemporal_load((const f32x4*)(p + 64));
        float s = va.x * va.x + va.y * va.y + va.z * va.z + va.w * va.w
                + vb.x * vb.x + vb.y * vb.y + vb.z * vb.z + vb.w * vb.w;
        // 16-lane butterfly sum (stays within each quarter of the wave)
        s += __shfl_xor(s, 1);
        s += __shfl_xor(s, 2);
        s += __shfl_xor(s, 4);
        s += __shfl_xor(s, 8);
        if (s > best_sum) {                   // strict: first max wins, like argmax
            best_sum = s;
            best_a   = va;
            best_b   = vb;
        }
    }

    // &out[b][n][sublane*4]
    float* o = out + ((size_t)b * NN + n) * (size_t)FF + (sublane << 2);
    __builtin_nontemporal_store(best_a, (f32x4*)o);
    __builtin_nontemporal_store(best_b, (f32x4*)(o + 64));
}

extern "C" void kernel_launch(void* const* d_in, const int* in_sizes, int n_in,
                              void* d_out, int out_size, void* d_ws, size_t ws_size,
                              hipStream_t stream) {
    const float* in  = (const float*)d_in[0];
    float*       out = (float*)d_out;

    // B*N/4 waves (each wave does 4 rows), 4 waves (256 threads) per block
    const int n_waves  = BB * NN / 4;         // 12288
    const int n_blocks = n_waves / 4;         // 3072

    amp_kernel<<<dim3(n_blocks), dim3(256), 0, stream>>>(in, out);
}